// Round 1
// baseline (1768.335 us; speedup 1.0000x reference)
//
#include <hip/hip_runtime.h>
#include <hip/hip_bf16.h>

#define NN 100000
#define NE 3200000
#define CI 128
#define NB 4

typedef __attribute__((ext_vector_type(8))) short bf16x8;
typedef __attribute__((ext_vector_type(4))) float f32x4;

__device__ __forceinline__ short f2bf(float f) {
  union { float f; unsigned u; } v; v.f = f;
  unsigned r = v.u + 0x7fffu + ((v.u >> 16) & 1u);  // RNE
  return (short)(r >> 16);
}

// ---------------- Kernel A: w0[n*4+b] = mean_k(key*query), fp32 ----------------
__global__ __launch_bounds__(256) void kA(const float* __restrict__ x,
                                          const float* __restrict__ Wk,
                                          const float* __restrict__ Wq,
                                          float* __restrict__ w0) {
  __shared__ float xs[256 * 32];  // XOR-swizzled: 256 nodes x 32-ch chunk
  const int b = blockIdx.y;
  const int n0 = blockIdx.x << 8;
  const int t = threadIdx.x;
  const float* xb = x + (size_t)b * NN * CI;
  float kacc[16], qacc[16];
#pragma unroll
  for (int k = 0; k < 16; ++k) { kacc[k] = 0.f; qacc[k] = 0.f; }
  for (int ch = 0; ch < 4; ++ch) {
    __syncthreads();
    // stage x[n0..n0+255][ch*32..+31], coalesced 128B rows, xor-swizzle slots
#pragma unroll
    for (int i = 0; i < 8; ++i) {
      int j = (i << 8) + t;
      int row = j >> 3, c4 = j & 7;
      int n = n0 + row;
      float4 v = make_float4(0.f, 0.f, 0.f, 0.f);
      if (n < NN) v = *(const float4*)(xb + (size_t)n * CI + (ch << 5) + (c4 << 2));
      *(float4*)(&xs[(row << 5) + ((c4 ^ (row & 7)) << 2)]) = v;
    }
    __syncthreads();
    float xr[32];
#pragma unroll
    for (int j = 0; j < 8; ++j) {
      float4 v = *(const float4*)(&xs[(t << 5) + ((j ^ (t & 7)) << 2)]);
      xr[4 * j + 0] = v.x; xr[4 * j + 1] = v.y; xr[4 * j + 2] = v.z; xr[4 * j + 3] = v.w;
    }
    const float* wkp = Wk + (ch << 5);  // uniform -> s_load
    const float* wqp = Wq + (ch << 5);
#pragma unroll
    for (int k = 0; k < 16; ++k) {
      float ka = kacc[k], qa = qacc[k];
#pragma unroll
      for (int c = 0; c < 32; ++c) {
        ka = fmaf(xr[c], wkp[k * CI + c], ka);
        qa = fmaf(xr[c], wqp[k * CI + c], qa);
      }
      kacc[k] = ka; qacc[k] = qa;
    }
  }
  float s = 0.f;
#pragma unroll
  for (int k = 0; k < 16; ++k) s = fmaf(kacc[k], qacc[k], s);
  int n = n0 + t;
  if (n < NN) w0[(n << 2) + b] = s * 0.0625f;
}

// ---------------- Kernel B: one SPMM round, wn[r] += 0.7*ev*wp[c] --------------
__global__ __launch_bounds__(256) void kB(const int* __restrict__ rows,
                                          const int* __restrict__ cols,
                                          const float* __restrict__ ev,
                                          const float* __restrict__ wp,
                                          float* __restrict__ wn) {
  int e = blockIdx.x * 256 + threadIdx.x;
  if (e >= NE) return;
  int r = rows[e], c = cols[e];
  float s = ev[e] * 0.7f;
  float4 w = *(const float4*)(wp + (c << 2));
  float* dst = wn + (r << 2);
  atomicAdd(dst + 0, s * w.x);
  atomicAdd(dst + 1, s * w.y);
  atomicAdd(dst + 2, s * w.z);
  atomicAdd(dst + 3, s * w.w);
}

// ------------- Kernel C: values = x*Wv^T (bf16 MFMA) -> *w -> LayerNorm -------
__global__ __launch_bounds__(256) void kC(const float* __restrict__ x,
                                          const float* __restrict__ Wv,
                                          const float* __restrict__ gamma,
                                          const float* __restrict__ beta,
                                          const float* __restrict__ w0,
                                          const float* __restrict__ w1,
                                          const float* __restrict__ w2,
                                          float* __restrict__ out) {
  __shared__ short wv[128 * 136];  // Wv as bf16, row stride 136 (272B, 16B-aligned)
  const int t = threadIdx.x;
  const int b = blockIdx.y;
  // stage Wv -> LDS bf16 (conflict-free b64 writes)
#pragma unroll
  for (int i = 0; i < 16; ++i) {
    int j = (i << 8) + t;  // 4096 float4
    int row = j >> 5, c4 = j & 31;
    float4 v = *(const float4*)(Wv + row * CI + (c4 << 2));
    short4 s4 = make_short4(f2bf(v.x), f2bf(v.y), f2bf(v.z), f2bf(v.w));
    *(short4*)(&wv[row * 136 + (c4 << 2)]) = s4;
  }
  __syncthreads();
  const int wave = t >> 6, lane = t & 63;
  const int n0 = ((blockIdx.x << 2) + wave) << 4;  // 16 nodes per wave
  if (n0 >= NN) return;                            // no further barriers
  const int l15 = lane & 15, quad = lane >> 4;
  // A-fragments: A[m=lane&15][k=quad*8+j] per 32-wide K chunk
  const float* xrow = x + (size_t)b * NN * CI + (size_t)(n0 + l15) * CI + (quad << 3);
  bf16x8 af[4];
#pragma unroll
  for (int ck = 0; ck < 4; ++ck) {
    float4 v0 = *(const float4*)(xrow + (ck << 5));
    float4 v1 = *(const float4*)(xrow + (ck << 5) + 4);
    bf16x8 a;
    a[0] = f2bf(v0.x); a[1] = f2bf(v0.y); a[2] = f2bf(v0.z); a[3] = f2bf(v0.w);
    a[4] = f2bf(v1.x); a[5] = f2bf(v1.y); a[6] = f2bf(v1.z); a[7] = f2bf(v1.w);
    af[ck] = a;
  }
  f32x4 acc[8];
#pragma unroll
  for (int o = 0; o < 8; ++o) acc[o] = (f32x4){0.f, 0.f, 0.f, 0.f};
#pragma unroll
  for (int ck = 0; ck < 4; ++ck) {
#pragma unroll
    for (int o = 0; o < 8; ++o) {  // B[k][n]: lane holds Wv[o*16+l15][ck*32+quad*8+j]
      bf16x8 bf = *(const bf16x8*)(&wv[((o << 4) + l15) * 136 + (ck << 5) + (quad << 3)]);
      acc[o] = __builtin_amdgcn_mfma_f32_16x16x32_bf16(af[ck], bf, acc[o], 0, 0, 0);
    }
  }
  // D layout: col = l15 (channel within o-tile), row = quad*4 + g (node)
  float wr[4];
#pragma unroll
  for (int g = 0; g < 4; ++g) {
    int idx = ((n0 + (quad << 2) + g) << 2) + b;
    wr[g] = w0[idx] + w1[idx] + w2[idx];
  }
  float vw[8][4], s1[4] = {0, 0, 0, 0}, s2[4] = {0, 0, 0, 0};
#pragma unroll
  for (int o = 0; o < 8; ++o)
#pragma unroll
    for (int g = 0; g < 4; ++g) {
      float v = acc[o][g] * wr[g];
      vw[o][g] = v;
      s1[g] += v;
      s2[g] = fmaf(v, v, s2[g]);
    }
  // reduce over the 16 lanes of each quad (they hold the other channels)
#pragma unroll
  for (int m = 1; m < 16; m <<= 1)
#pragma unroll
    for (int g = 0; g < 4; ++g) {
      s1[g] += __shfl_xor(s1[g], m, 64);
      s2[g] += __shfl_xor(s2[g], m, 64);
    }
  float mu[4], rs[4];
#pragma unroll
  for (int g = 0; g < 4; ++g) {
    mu[g] = s1[g] * (1.f / 128.f);
    float var = s2[g] * (1.f / 128.f) - mu[g] * mu[g];
    rs[g] = rsqrtf(var + 1e-5f);
  }
  float* ob = out + (size_t)b * NN * CI + (size_t)n0 * CI;
#pragma unroll
  for (int o = 0; o < 8; ++o) {
    int c = (o << 4) + l15;
    float ga = gamma[c], be = beta[c];
#pragma unroll
    for (int g = 0; g < 4; ++g) {
      int r = (quad << 2) + g;
      ob[(size_t)r * CI + c] = (vw[o][g] - mu[g]) * rs[g] * ga + be;
    }
  }
}

extern "C" void kernel_launch(void* const* d_in, const int* in_sizes, int n_in,
                              void* d_out, int out_size, void* d_ws, size_t ws_size,
                              hipStream_t stream) {
  const float* x     = (const float*)d_in[0];
  const float* Wk    = (const float*)d_in[1];
  const float* Wq    = (const float*)d_in[2];
  const float* Wv    = (const float*)d_in[3];
  const float* gamma = (const float*)d_in[4];
  const float* beta  = (const float*)d_in[5];
  const float* ev    = (const float*)d_in[6];
  const int*   ei    = (const int*)d_in[7];  // int64 in source -> int32 on device (JAX x64 off)
  float* out = (float*)d_out;

  float* w0 = (float*)d_ws;           // [NN*4]
  float* w1 = w0 + NN * 4;            // [NN*4]
  float* w2 = w1 + NN * 4;            // [NN*4]

  hipMemsetAsync(w1, 0, (size_t)2 * NN * 4 * sizeof(float), stream);

  dim3 gA((NN + 255) / 256, NB);
  kA<<<gA, 256, 0, stream>>>(x, Wk, Wq, w0);

  kB<<<(NE + 255) / 256, 256, 0, stream>>>(ei, ei + NE, ev, w0, w1);
  kB<<<(NE + 255) / 256, 256, 0, stream>>>(ei, ei + NE, ev, w1, w2);

  dim3 gC((NN / 16 + 3) / 4, NB);
  kC<<<gC, 256, 0, stream>>>(x, Wv, gamma, beta, w0, w1, w2, out);
}

// Round 2
// 747.236 us; speedup vs baseline: 2.3665x; 2.3665x over previous
//
#include <hip/hip_runtime.h>
#include <hip/hip_bf16.h>

#define NN 100000
#define NE 3200000
#define CI 128
#define NB 4

// SPMM bucketing
#define NBKT 256
#define RPB 391      // ceil(NN / NBKT)
#define P2BLK 256
#define CHUNK 12500  // NE / P2BLK

typedef __attribute__((ext_vector_type(8))) short bf16x8;
typedef __attribute__((ext_vector_type(4))) float f32x4;

__device__ __forceinline__ short f2bf(float f) {
  union { float f; unsigned u; } v; v.f = f;
  unsigned r = v.u + 0x7fffu + ((v.u >> 16) & 1u);  // RNE
  return (short)(r >> 16);
}

// ---------------- Kernel A: w0[n*4+b] = mean_k(key*query), fp32 ----------------
__global__ __launch_bounds__(256) void kA(const float* __restrict__ x,
                                          const float* __restrict__ Wk,
                                          const float* __restrict__ Wq,
                                          float* __restrict__ w0) {
  __shared__ float xs[256 * 32];  // XOR-swizzled: 256 nodes x 32-ch chunk
  const int b = blockIdx.y;
  const int n0 = blockIdx.x << 8;
  const int t = threadIdx.x;
  const float* xb = x + (size_t)b * NN * CI;
  float kacc[16], qacc[16];
#pragma unroll
  for (int k = 0; k < 16; ++k) { kacc[k] = 0.f; qacc[k] = 0.f; }
  for (int ch = 0; ch < 4; ++ch) {
    __syncthreads();
#pragma unroll
    for (int i = 0; i < 8; ++i) {
      int j = (i << 8) + t;
      int row = j >> 3, c4 = j & 7;
      int n = n0 + row;
      float4 v = make_float4(0.f, 0.f, 0.f, 0.f);
      if (n < NN) v = *(const float4*)(xb + (size_t)n * CI + (ch << 5) + (c4 << 2));
      *(float4*)(&xs[(row << 5) + ((c4 ^ (row & 7)) << 2)]) = v;
    }
    __syncthreads();
    float xr[32];
#pragma unroll
    for (int j = 0; j < 8; ++j) {
      float4 v = *(const float4*)(&xs[(t << 5) + ((j ^ (t & 7)) << 2)]);
      xr[4 * j + 0] = v.x; xr[4 * j + 1] = v.y; xr[4 * j + 2] = v.z; xr[4 * j + 3] = v.w;
    }
    const float* wkp = Wk + (ch << 5);  // uniform -> s_load
    const float* wqp = Wq + (ch << 5);
#pragma unroll
    for (int k = 0; k < 16; ++k) {
      float ka = kacc[k], qa = qacc[k];
#pragma unroll
      for (int c = 0; c < 32; ++c) {
        ka = fmaf(xr[c], wkp[k * CI + c], ka);
        qa = fmaf(xr[c], wqp[k * CI + c], qa);
      }
      kacc[k] = ka; qacc[k] = qa;
    }
  }
  float s = 0.f;
#pragma unroll
  for (int k = 0; k < 16; ++k) s = fmaf(kacc[k], qacc[k], s);
  int n = n0 + t;
  if (n < NN) w0[(n << 2) + b] = s * 0.0625f;
}

// ------------- SPMM phase 1: per-(bucket,block) histogram ----------------------
__global__ __launch_bounds__(256) void kCount(const int* __restrict__ rows,
                                              int* __restrict__ cnt) {
  __shared__ int hist[NBKT];
  const int t = threadIdx.x;
  hist[t] = 0;
  __syncthreads();
  const int e0 = blockIdx.x * CHUNK;
  for (int i = t; i < CHUNK; i += 256) {
    int r = rows[e0 + i];
    atomicAdd(&hist[r / RPB], 1);
  }
  __syncthreads();
  cnt[t * P2BLK + blockIdx.x] = hist[t];
}

// ------------- SPMM phase 2: prefix sums (single block) ------------------------
__global__ __launch_bounds__(256) void kScan(int* __restrict__ cnt,
                                             int* __restrict__ bktbase) {
  __shared__ int tot[NBKT];
  const int t = threadIdx.x;
  int run = 0;
  for (int b = 0; b < P2BLK; ++b) {
    int v = cnt[t * P2BLK + b];
    cnt[t * P2BLK + b] = run;   // within-bucket exclusive prefix over blocks
    run += v;
  }
  tot[t] = run;
  __syncthreads();
  if (t == 0) {
    int acc = 0;
    for (int i = 0; i < NBKT; ++i) { bktbase[i] = acc; acc += tot[i]; }
    bktbase[NBKT] = acc;
  }
}

// ------------- SPMM phase 3: scatter into bucket-contiguous arrays -------------
__global__ __launch_bounds__(256) void kScatter(const int* __restrict__ rows,
                                                const int* __restrict__ cols,
                                                const float* __restrict__ ev,
                                                const int* __restrict__ cnt,
                                                const int* __restrict__ bktbase,
                                                unsigned* __restrict__ keys,
                                                float* __restrict__ vals) {
  __shared__ int cur[NBKT];
  const int t = threadIdx.x;
  cur[t] = bktbase[t] + cnt[t * P2BLK + blockIdx.x];
  __syncthreads();
  const int e0 = blockIdx.x * CHUNK;
  for (int i = t; i < CHUNK; i += 256) {
    int e = e0 + i;
    int r = rows[e], c = cols[e];
    float v = ev[e] * 0.7f;           // fold DECAY once per round's use
    int bkt = r / RPB;
    int rl = r - bkt * RPB;
    int pos = atomicAdd(&cur[bkt], 1);
    keys[pos] = ((unsigned)rl << 17) | (unsigned)c;
    vals[pos] = v;
  }
}

// ------------- SPMM phase 4: per-bucket LDS accumulate (x2 rounds) -------------
__global__ __launch_bounds__(512) void kSpmm(const unsigned* __restrict__ keys,
                                             const float* __restrict__ vals,
                                             const int* __restrict__ bktbase,
                                             const float* __restrict__ wp,
                                             float* __restrict__ wn) {
  __shared__ float acc[RPB * 4];
  const int t = threadIdx.x;
  const int bkt = blockIdx.x;
  for (int i = t; i < RPB * 4; i += 512) acc[i] = 0.f;
  __syncthreads();
  const int e1 = bktbase[bkt + 1];
  for (int e = bktbase[bkt] + t; e < e1; e += 512) {
    unsigned k = keys[e];
    float v = vals[e];
    int c = k & 0x1FFFF;
    int rl = k >> 17;
    float4 w = *(const float4*)(wp + (c << 2));
    atomicAdd(&acc[rl * 4 + 0], v * w.x);
    atomicAdd(&acc[rl * 4 + 1], v * w.y);
    atomicAdd(&acc[rl * 4 + 2], v * w.z);
    atomicAdd(&acc[rl * 4 + 3], v * w.w);
  }
  __syncthreads();
  const int base = bkt * RPB;
  const int nw = min(RPB, NN - base) * 4;
  for (int i = t; i < nw; i += 512)
    wn[(base << 2) + i] = acc[i];
}

// ------------- Kernel C: values = x*Wv^T (bf16 MFMA) -> *w -> LayerNorm -------
__global__ __launch_bounds__(256) void kC(const float* __restrict__ x,
                                          const float* __restrict__ Wv,
                                          const float* __restrict__ gamma,
                                          const float* __restrict__ beta,
                                          const float* __restrict__ w0,
                                          const float* __restrict__ w1,
                                          const float* __restrict__ w2,
                                          float* __restrict__ out) {
  __shared__ short wv[128 * 136];  // Wv as bf16, row stride 136
  const int t = threadIdx.x;
  const int b = blockIdx.y;
#pragma unroll
  for (int i = 0; i < 16; ++i) {
    int j = (i << 8) + t;
    int row = j >> 5, c4 = j & 31;
    float4 v = *(const float4*)(Wv + row * CI + (c4 << 2));
    short4 s4 = make_short4(f2bf(v.x), f2bf(v.y), f2bf(v.z), f2bf(v.w));
    *(short4*)(&wv[row * 136 + (c4 << 2)]) = s4;
  }
  __syncthreads();
  const int wave = t >> 6, lane = t & 63;
  const int n0 = ((blockIdx.x << 2) + wave) << 4;
  if (n0 >= NN) return;
  const int l15 = lane & 15, quad = lane >> 4;
  const float* xrow = x + (size_t)b * NN * CI + (size_t)(n0 + l15) * CI + (quad << 3);
  bf16x8 af[4];
#pragma unroll
  for (int ck = 0; ck < 4; ++ck) {
    float4 v0 = *(const float4*)(xrow + (ck << 5));
    float4 v1 = *(const float4*)(xrow + (ck << 5) + 4);
    bf16x8 a;
    a[0] = f2bf(v0.x); a[1] = f2bf(v0.y); a[2] = f2bf(v0.z); a[3] = f2bf(v0.w);
    a[4] = f2bf(v1.x); a[5] = f2bf(v1.y); a[6] = f2bf(v1.z); a[7] = f2bf(v1.w);
    af[ck] = a;
  }
  f32x4 acc[8];
#pragma unroll
  for (int o = 0; o < 8; ++o) acc[o] = (f32x4){0.f, 0.f, 0.f, 0.f};
#pragma unroll
  for (int ck = 0; ck < 4; ++ck) {
#pragma unroll
    for (int o = 0; o < 8; ++o) {
      bf16x8 bf = *(const bf16x8*)(&wv[((o << 4) + l15) * 136 + (ck << 5) + (quad << 3)]);
      acc[o] = __builtin_amdgcn_mfma_f32_16x16x32_bf16(af[ck], bf, acc[o], 0, 0, 0);
    }
  }
  float wr[4];
#pragma unroll
  for (int g = 0; g < 4; ++g) {
    int idx = ((n0 + (quad << 2) + g) << 2) + b;
    wr[g] = w0[idx] + w1[idx] + w2[idx];
  }
  float vw[8][4], s1[4] = {0, 0, 0, 0}, s2[4] = {0, 0, 0, 0};
#pragma unroll
  for (int o = 0; o < 8; ++o)
#pragma unroll
    for (int g = 0; g < 4; ++g) {
      float v = acc[o][g] * wr[g];
      vw[o][g] = v;
      s1[g] += v;
      s2[g] = fmaf(v, v, s2[g]);
    }
#pragma unroll
  for (int m = 1; m < 16; m <<= 1)
#pragma unroll
    for (int g = 0; g < 4; ++g) {
      s1[g] += __shfl_xor(s1[g], m, 64);
      s2[g] += __shfl_xor(s2[g], m, 64);
    }
  float mu[4], rs[4];
#pragma unroll
  for (int g = 0; g < 4; ++g) {
    mu[g] = s1[g] * (1.f / 128.f);
    float var = s2[g] * (1.f / 128.f) - mu[g] * mu[g];
    rs[g] = rsqrtf(var + 1e-5f);
  }
  float* ob = out + (size_t)b * NN * CI + (size_t)n0 * CI;
#pragma unroll
  for (int o = 0; o < 8; ++o) {
    int c = (o << 4) + l15;
    float ga = gamma[c], be = beta[c];
#pragma unroll
    for (int g = 0; g < 4; ++g) {
      int r = (quad << 2) + g;
      ob[(size_t)r * CI + c] = (vw[o][g] - mu[g]) * rs[g] * ga + be;
    }
  }
}

extern "C" void kernel_launch(void* const* d_in, const int* in_sizes, int n_in,
                              void* d_out, int out_size, void* d_ws, size_t ws_size,
                              hipStream_t stream) {
  const float* x     = (const float*)d_in[0];
  const float* Wk    = (const float*)d_in[1];
  const float* Wq    = (const float*)d_in[2];
  const float* Wv    = (const float*)d_in[3];
  const float* gamma = (const float*)d_in[4];
  const float* beta  = (const float*)d_in[5];
  const float* ev    = (const float*)d_in[6];
  const int*   ei    = (const int*)d_in[7];  // int64 in source -> int32 on device
  float* out = (float*)d_out;

  float* w0 = (float*)d_ws;                 // [NN*4]
  float* w1 = w0 + NN * 4;                  // [NN*4]
  float* w2 = w1 + NN * 4;                  // [NN*4]
  unsigned* keys = (unsigned*)(w2 + NN * 4);// [NE]
  float* vals = (float*)(keys + NE);        // [NE]
  int* cnt = (int*)(vals + NE);             // [NBKT*P2BLK]
  int* bktbase = cnt + NBKT * P2BLK;        // [NBKT+1]

  const int* rows = ei;
  const int* cols = ei + NE;

  dim3 gA((NN + 255) / 256, NB);
  kA<<<gA, 256, 0, stream>>>(x, Wk, Wq, w0);

  kCount<<<P2BLK, 256, 0, stream>>>(rows, cnt);
  kScan<<<1, 256, 0, stream>>>(cnt, bktbase);
  kScatter<<<P2BLK, 256, 0, stream>>>(rows, cols, ev, cnt, bktbase, keys, vals);
  kSpmm<<<NBKT, 512, 0, stream>>>(keys, vals, bktbase, w0, w1);
  kSpmm<<<NBKT, 512, 0, stream>>>(keys, vals, bktbase, w1, w2);

  dim3 gC((NN / 16 + 3) / 4, NB);
  kC<<<gC, 256, 0, stream>>>(x, Wv, gamma, beta, w0, w1, w2, out);
}